// Round 12
// baseline (792.935 us; speedup 1.0000x reference)
//
#include <hip/hip_runtime.h>
#include <hip/hip_bf16.h>
#include <stdint.h>

#define NT   8192
#define DIN  2048
#define DOUT 2048
#define NSP  8
#define BK   64

// fp16 MFMA fragments: 8 halves = 4 VGPRs (guide §3, same mapping as bf16).
typedef _Float16 f16x8 __attribute__((ext_vector_type(8)));
typedef float    f32x4 __attribute__((ext_vector_type(4)));

static_assert(sizeof(f16x8) == 16, "f16x8 must be 16B");

__device__ __forceinline__ f32x4 mfma_f16(f16x8 a, f16x8 b, f32x4 c) {
  return __builtin_amdgcn_mfma_f32_16x16x32_f16(a, b, c, 0, 0, 0);
}

// async global->LDS, 16B per lane. HW semantics (m104/m108): dest is
// wave-uniform base + lane*16 — our per-lane loff is exactly lane-linear.
__device__ __forceinline__ void async16(const void* g, void* l) {
  __builtin_amdgcn_global_load_lds(
      (const __attribute__((address_space(1))) uint32_t*)g,
      (__attribute__((address_space(3))) uint32_t*)l, 16, 0, 0);
}

// ---------------- x convert: fp32 [T][D] -> fp16 [T][D] ----------------------
__global__ void k_convert_x(const float* __restrict__ x,
                            _Float16* __restrict__ xh) {
  int idx = blockIdx.x * blockDim.x + threadIdx.x;  // 8 elems / thread
  const float4* xv = (const float4*)x;
  float4 v0 = xv[2 * idx], v1 = xv[2 * idx + 1];
  union { _Float16 h[8]; int4 q; } H;
  H.h[0] = (_Float16)v0.x; H.h[1] = (_Float16)v0.y;
  H.h[2] = (_Float16)v0.z; H.h[3] = (_Float16)v0.w;
  H.h[4] = (_Float16)v1.x; H.h[5] = (_Float16)v1.y;
  H.h[6] = (_Float16)v1.z; H.h[7] = (_Float16)v1.w;
  ((int4*)xh)[idx] = H.q;
}

// ---- W convert+transpose, ALL 9 experts in one launch: z=0 shared, 1..8 sp --
// 64x64 tile: float4 coalesced loads -> LDS fp16 (stride 66: write phase
// spreads all 32 banks; read phase 4-way, acceptable) -> int4 coalesced stores.
__global__ void k_convert_w9(const float* __restrict__ Wsh,
                             const float* __restrict__ Wsp,
                             _Float16* __restrict__ wth) {
  __shared__ _Float16 sh[64 * 66];
  const int z = blockIdx.z;
  const float* Wm = (z == 0) ? Wsh : (Wsp + (size_t)(z - 1) * DIN * DOUT);
  const int k0 = blockIdx.x * 64, o0 = blockIdx.y * 64;
  const int t = threadIdx.x;
  const int kr = t >> 4, oc4 = (t & 15) * 4;   // load: 16 k-rows/pass, 4 passes
#pragma unroll
  for (int i = 0; i < 4; i++) {
    int k = kr + i * 16;
    float4 v = *(const float4*)&Wm[(size_t)(k0 + k) * DOUT + o0 + oc4];
    sh[k * 66 + oc4 + 0] = (_Float16)v.x;
    sh[k * 66 + oc4 + 1] = (_Float16)v.y;
    sh[k * 66 + oc4 + 2] = (_Float16)v.z;
    sh[k * 66 + oc4 + 3] = (_Float16)v.w;
  }
  __syncthreads();
  const int orow = t >> 3, kq = t & 7;         // store: 32 o-rows/pass, 2 passes
  const size_t obase = (size_t)z * DOUT;
#pragma unroll
  for (int i = 0; i < 2; i++) {
    int o = orow + i * 32;
    union { _Float16 h[8]; int4 q; } P;
#pragma unroll
    for (int j = 0; j < 8; j++) P.h[j] = sh[(kq * 8 + j) * 66 + o];
    *(int4*)&wth[(obase + o0 + o) * (size_t)DIN + (size_t)(k0 + kq * 8)] = P.q;
  }
}

// ---------------- router: gates + per-expert token lists ---------------------
__global__ void k_router(const float* __restrict__ x, const float* __restrict__ Wr,
                         const float* __restrict__ br,
                         int* __restrict__ counts, int* __restrict__ tok_list,
                         float* __restrict__ w_list) {
  const int wave = threadIdx.x >> 6, lane = threadIdx.x & 63;
  const int t = blockIdx.x * 4 + wave;
  const float* xrow = x + (size_t)t * DIN;
  float acc[NSP];
#pragma unroll
  for (int e = 0; e < NSP; e++) acc[e] = 0.f;
  for (int d = lane; d < DIN; d += 64) {
    float xv = xrow[d];
    const float* wr = Wr + d * NSP;
#pragma unroll
    for (int e = 0; e < NSP; e++) acc[e] += xv * wr[e];
  }
#pragma unroll
  for (int e = 0; e < NSP; e++) {
#pragma unroll
    for (int off = 32; off > 0; off >>= 1) acc[e] += __shfl_xor(acc[e], off, 64);
  }
  if (lane == 0) {
    float lg[NSP], mx = -1e30f;
#pragma unroll
    for (int e = 0; e < NSP; e++) { lg[e] = acc[e] + br[e]; mx = fmaxf(mx, lg[e]); }
    float p[NSP], s = 0.f;
#pragma unroll
    for (int e = 0; e < NSP; e++) { p[e] = expf(lg[e] - mx); s += p[e]; }
    int i0 = 0;
#pragma unroll
    for (int e = 1; e < NSP; e++) if (p[e] > p[i0]) i0 = e;   // strict >: first max
    int i1 = (i0 == 0) ? 1 : 0;                               // == lax.top_k ties
#pragma unroll
    for (int e = 0; e < NSP; e++) if (e != i0 && p[e] > p[i1]) i1 = e;
    float p0 = p[i0] / s, p1 = p[i1] / s;
    float denom = p0 + p1 + 1e-6f;
    float w0 = p0 / denom, w1 = p1 / denom;
    int s0 = atomicAdd(&counts[i0], 1);
    tok_list[i0 * NT + s0] = t; w_list[i0 * NT + s0] = w0;
    int s1 = atomicAdd(&counts[i1], 1);
    tok_list[i1 * NT + s1] = t; w_list[i1 * NT + s1] = w1;
  }
}

// ------------- fp16 MFMA GEMM (m97 shape: 128x128 tile, BK=64, 4 waves) ------
// Grid: x = ROW-tiles (64, fastest-varying), y = COL-tiles (16). XCD swizzle
// (T1, m157/m204): each XCD gets a contiguous chunk of (col-pair x all rows),
// so early-exit sparse rows stay BALANCED across XCDs and each XCD's B-panels
// (2 cols x 512KB) are L2-resident and fetched once.
template <bool SPARSE>
__global__ __launch_bounds__(256, 4) void k_moe_gemm(
    const _Float16* __restrict__ xh, const _Float16* __restrict__ wth,
    const float* __restrict__ bias, const int* __restrict__ counts,
    const int* __restrict__ tok_list, const float* __restrict__ w_list,
    float* __restrict__ y) {
  const int e = SPARSE ? blockIdx.z : 0;
  const int wi = SPARSE ? (1 + e) : 0;

  // XCD chunk swizzle: bid = dispatch-linear id within the z-slice (x fastest).
  // nwg = 64*16 = 1024, divisible by 8 -> bijective (m157 form).
  const int nx = gridDim.x;                              // 64 row-tiles
  const int bid = blockIdx.y * nx + blockIdx.x;
  const int cpx = (nx * gridDim.y) >> 3;                 // 128 blocks/XCD
  const int swz = (bid & 7) * cpx + (bid >> 3);
  const int row0 = (swz % nx) * 128;                     // rows fastest in swz
  const int col0 = (swz / nx) * 128;

  int cnt = NT;
  if (SPARSE) {
    cnt = counts[e];
    if (row0 >= cnt) return;
  }

  __shared__ __align__(16) _Float16 sA[128 * BK];
  __shared__ __align__(16) _Float16 sB[128 * BK];
  __shared__ int   s_tok[128];
  __shared__ float s_w[128];

  const int tid = threadIdx.x;
  const int wave = tid >> 6, lane = tid & 63;

  if (SPARSE) {
    if (tid < 128) {
      int slot = row0 + tid;
      int tk = 0; float w = 0.f;
      if (slot < cnt) { tk = tok_list[e * NT + slot]; w = w_list[e * NT + slot]; }
      s_tok[tid] = tk; s_w[tid] = w;
    }
    __syncthreads();
  }

  // Staging: wave owns rows [wave*32,+32), 4 issues x 8 rows per array.
  // Row = 128B = 8 chunks of 16B; physical slot p holds logical chunk p^(r&7).
  // Source pre-swizzled so LDS dest stays lane-linear (m173 / rule #21).
  const int lr = lane >> 3, pp = lane & 7;
  const _Float16* gA[4]; const _Float16* gB[4];
  int loff[4];
#pragma unroll
  for (int j = 0; j < 4; j++) {
    int r = wave * 32 + j * 8 + lr;
    int xoff = ((pp ^ (r & 7)) << 3);  // element offset of swizzled 8-elem chunk
    int tk = SPARSE ? s_tok[r] : (row0 + r);
    gA[j] = xh + (size_t)tk * DIN + xoff;
    gB[j] = wth + ((size_t)wi * DOUT + (size_t)(col0 + r)) * DIN + xoff;
    loff[j] = r * BK + pp * 8;  // fp16 index; byte = r*128 + pp*16
  }

  f32x4 acc[4][4];
#pragma unroll
  for (int m = 0; m < 4; m++)
#pragma unroll
    for (int n = 0; n < 4; n++) acc[m][n] = (f32x4){0.f, 0.f, 0.f, 0.f};

  const int wm = (wave >> 1) * 64, wn = (wave & 1) * 64;
  const int fr = lane & 15, fg = lane >> 4;   // frag row / 8-elem k-group

  for (int kt = 0; kt < DIN / BK; kt++) {
    const int k0 = kt * BK;
#pragma unroll
    for (int j = 0; j < 4; j++) {
      async16(gA[j] + k0, &sA[loff[j]]);
      async16(gB[j] + k0, &sB[loff[j]]);
    }
    __syncthreads();  // compiler drains vmcnt before barrier

#pragma unroll
    for (int ks = 0; ks < 2; ks++) {
      f16x8 ah[4], bh[4];
#pragma unroll
      for (int m = 0; m < 4; m++) {
        int r = wm + m * 16 + fr;
        int sl = (((ks * 4 + fg) ^ (r & 7)) << 3);
        ah[m] = *(const f16x8*)&sA[r * BK + sl];
      }
#pragma unroll
      for (int n = 0; n < 4; n++) {
        int c = wn + n * 16 + fr;
        int sl = (((ks * 4 + fg) ^ (c & 7)) << 3);
        bh[n] = *(const f16x8*)&sB[c * BK + sl];
      }
#pragma unroll
      for (int m = 0; m < 4; m++)
#pragma unroll
        for (int n = 0; n < 4; n++)
          acc[m][n] = mfma_f16(ah[m], bh[n], acc[m][n]);
    }
    __syncthreads();
  }

  // Epilogue. C/D layout: col = lane&15, row = (lane>>4)*4 + reg (m89-verified).
#pragma unroll
  for (int n = 0; n < 4; n++) {
    int col = col0 + wn + n * 16 + fr;
    float bc = SPARSE ? bias[e * DOUT + col] : bias[col];
#pragma unroll
    for (int m = 0; m < 4; m++) {
#pragma unroll
      for (int q = 0; q < 4; q++) {
        int lrow = wm + m * 16 + fg * 4 + q;
        float v = acc[m][n][q];
        if (SPARSE) {
          if (row0 + lrow < cnt) {
            float g = s_w[lrow];
            atomicAdd(&y[(size_t)s_tok[lrow] * DOUT + col], g * (v + bc));
          }
        } else {
          y[(size_t)(row0 + lrow) * DOUT + col] = v + bc;  // N_SHARED==1
        }
      }
    }
  }
}

// ============ Tier-B fallback: fp32 vector GEMM, tiny workspace ==============
template <bool SPARSE>
__global__ void k_fb_gemm(const float* __restrict__ x, const float* __restrict__ W,
                          const float* __restrict__ bias,
                          const int* __restrict__ counts,
                          const int* __restrict__ tok_list,
                          const float* __restrict__ w_list,
                          float* __restrict__ y) {
  const int e = SPARSE ? blockIdx.z : 0;
  int cnt = NT;
  if (SPARSE) {
    cnt = counts[e];
    if ((int)blockIdx.y * 64 >= cnt) return;
  }
  const int row0 = blockIdx.y * 64, col0 = blockIdx.x * 64;
  const float* Wm = W + (SPARSE ? (size_t)e * DIN * DOUT : 0);

  __shared__ float sA[64][17];
  __shared__ float sB[16][65];
  __shared__ int   s_tok[64];
  __shared__ float s_w[64];

  const int tid = threadIdx.x;
  if (SPARSE) {
    if (tid < 64) {
      int slot = row0 + tid;
      int tk = 0; float w = 0.f;
      if (slot < cnt) { tk = tok_list[e * NT + slot]; w = w_list[e * NT + slot]; }
      s_tok[tid] = tk; s_w[tid] = w;
    }
    __syncthreads();
  }

  const int ar = tid >> 2, ak = (tid & 3) * 4;
  const int bk = tid >> 4, bc4 = (tid & 15) * 4;
  const int tm = tid >> 4, tn = tid & 15;

  float acc[4][4];
#pragma unroll
  for (int m = 0; m < 4; m++)
#pragma unroll
    for (int n = 0; n < 4; n++) acc[m][n] = 0.f;

  const int tkA = SPARSE ? s_tok[ar] : (row0 + ar);

  for (int k0 = 0; k0 < DIN; k0 += 16) {
    float4 va = *(const float4*)&x[(size_t)tkA * DIN + k0 + ak];
    float4 vb = *(const float4*)&Wm[(size_t)(k0 + bk) * DOUT + col0 + bc4];
    sA[ar][ak]     = va.x; sA[ar][ak + 1] = va.y;
    sA[ar][ak + 2] = va.z; sA[ar][ak + 3] = va.w;
    sB[bk][bc4]     = vb.x; sB[bk][bc4 + 1] = vb.y;
    sB[bk][bc4 + 2] = vb.z; sB[bk][bc4 + 3] = vb.w;
    __syncthreads();
#pragma unroll
    for (int kk = 0; kk < 16; kk++) {
      float a0 = sA[tm * 4 + 0][kk], a1 = sA[tm * 4 + 1][kk];
      float a2 = sA[tm * 4 + 2][kk], a3 = sA[tm * 4 + 3][kk];
#pragma unroll
      for (int n = 0; n < 4; n++) {
        float b = sB[kk][tn * 4 + n];
        acc[0][n] += a0 * b; acc[1][n] += a1 * b;
        acc[2][n] += a2 * b; acc[3][n] += a3 * b;
      }
    }
    __syncthreads();
  }

#pragma unroll
  for (int m = 0; m < 4; m++) {
    int lrow = tm * 4 + m;
#pragma unroll
    for (int n = 0; n < 4; n++) {
      int col = col0 + tn * 4 + n;
      float bcv = SPARSE ? bias[e * DOUT + col] : bias[col];
      if (SPARSE) {
        if (row0 + lrow < cnt) {
          atomicAdd(&y[(size_t)s_tok[lrow] * DOUT + col],
                    s_w[lrow] * (acc[m][n] + bcv));
        }
      } else {
        y[(size_t)(row0 + lrow) * DOUT + col] = acc[m][n] + bcv;
      }
    }
  }
}

// Tier-C: zero d_out (safe, loud validation failure — never faults).
__global__ void k_zero(float* __restrict__ y, int n) {
  for (int i = blockIdx.x * blockDim.x + threadIdx.x; i < n;
       i += gridDim.x * blockDim.x)
    y[i] = 0.f;
}

extern "C" void kernel_launch(void* const* d_in, const int* in_sizes, int n_in,
                              void* d_out, int out_size, void* d_ws, size_t ws_size,
                              hipStream_t stream) {
  (void)in_sizes; (void)n_in;
  const float* x   = (const float*)d_in[0];
  const float* Wsh = (const float*)d_in[1];
  const float* bsh = (const float*)d_in[2];
  const float* Wr  = (const float*)d_in[3];
  const float* br  = (const float*)d_in[4];
  const float* Wsp = (const float*)d_in[5];
  const float* bsp = (const float*)d_in[6];
  float* y = (float*)d_out;

  char* ws = (char*)d_ws;
  size_t off = 0;
  auto alloc = [&](size_t bytes) {
    off = (off + 255) & ~(size_t)255;
    void* p = ws + off;
    off += bytes;
    return p;
  };
  int*      counts   = (int*)alloc(NSP * sizeof(int));
  int*      tok_list = (int*)alloc((size_t)NSP * NT * sizeof(int));
  float*    w_list   = (float*)alloc((size_t)NSP * NT * sizeof(float));
  const size_t NEED_FB = off;                     // ~0.53 MB
  _Float16* xh       = (_Float16*)alloc((size_t)NT * DIN * 2);
  _Float16* wth      = (_Float16*)alloc((size_t)9 * DOUT * DIN * 2);
  const size_t NEED_FAST = off;                   // ~110 MB

  if (ws_size < NEED_FB) {                        // Tier C: no usable scratch
    k_zero<<<2048, 256, 0, stream>>>(y, out_size);
    return;
  }

  hipMemsetAsync(counts, 0, NSP * sizeof(int), stream);
  k_router<<<NT / 4, 256, 0, stream>>>(x, Wr, br, counts, tok_list, w_list);

  if (ws_size >= NEED_FAST) {                     // Tier A: fp16 MFMA path
    k_convert_x<<<(NT * DIN / 8) / 256, 256, 0, stream>>>(x, xh);
    k_convert_w9<<<dim3(DIN / 64, DOUT / 64, 9), 256, 0, stream>>>(Wsh, Wsp, wth);
    // shared expert: plain store (initializes all of y)
    k_moe_gemm<false><<<dim3(NT / 128, DOUT / 128, 1), 256, 0, stream>>>(
        xh, wth, bsh, counts, tok_list, w_list, y);
    // sparse experts: gathered rows, atomicAdd epilogue (ordered after shared)
    k_moe_gemm<true><<<dim3(NT / 128, DOUT / 128, NSP), 256, 0, stream>>>(
        xh, wth, bsp, counts, tok_list, w_list, y);
  } else {                                        // Tier B: fp32 fallback GEMM
    k_fb_gemm<false><<<dim3(DOUT / 64, NT / 64, 1), 256, 0, stream>>>(
        x, Wsh, bsh, counts, tok_list, w_list, y);
    k_fb_gemm<true><<<dim3(DOUT / 64, NT / 64, NSP), 256, 0, stream>>>(
        x, Wsp, bsp, counts, tok_list, w_list, y);
  }
}